// Round 9
// baseline (865.457 us; speedup 1.0000x reference)
//
#include <hip/hip_runtime.h>

#define MAX_SR 3
#define TSZ 8   // TEMPLATE_SZ

// out[(((b*H+h)*W + w)*CV2 + d)*64 + e] = (int)Pzero[b, h+base+dy+ky, w+base+dx+kx]
// d = dy*CV+dx, e = ky*8+kx, base = -(sr + TSZ/2). Output int32.
//
// v3: block = (b, h, 80-wide w segment). Stage the (CV+7) x (80+CV+7) patch
// in LDS once, then 125 iterations (cv=5) of perfectly sequential stores:
// iteration s, thread tid writes int4 index f = s*256+tid of the block's
// contiguous 512 KB output window. 1536 blocks = exactly 6 per CU.
template<int CV>
__global__ __launch_bounds__(256) void esw_v3(
    const float* __restrict__ x, int* __restrict__ out,
    int H, int W, int base)
{
    constexpr int CV2   = CV * CV;
    constexpr int WSEG  = 80;
    constexpr int ROWS  = CV + 7;            // 12 for cv=5
    constexpr int COLS  = WSEG + CV + 7;     // 92 for cv=5
    constexpr int PITCH = COLS | 1;          // odd pitch (93) -> conflict-light
    constexpr int NS    = WSEG * CV2 * 16 / 256;   // 125 for cv=5
    __shared__ float smem[ROWS * PITCH];

    const int q  = blockIdx.x;               // w-segment
    const int h  = blockIdx.y;
    const int b  = blockIdx.z;
    const int w0 = q * WSEG;

    // ---- stage input patch (zero-padded), coalesced per row ----
    const float* __restrict__ xb = x + (size_t)b * H * W;
    for (int i = threadIdx.x; i < ROWS * COLS; i += 256) {
        int r  = i / COLS;                   // compile-time divisor
        int c  = i - r * COLS;
        int yy = h + base + r;
        int xx = w0 + base + c;
        float v = 0.0f;
        if ((unsigned)yy < (unsigned)H && (unsigned)xx < (unsigned)W)
            v = xb[yy * W + xx];
        smem[r * PITCH + c] = v;
    }
    __syncthreads();

    const int tid = threadIdx.x;
    const int t   = tid & 15;                // e-quad: e = t*4 + j
    const int hi  = tid >> 4;
    const int ky  = t >> 1;
    const int kx0 = (t & 1) << 2;

    int* __restrict__ ob =
        out + (((size_t)b * H + h) * W + w0) * (size_t)(CV2 * 64);
    const float* __restrict__ sb = smem + ky * PITCH + kx0;

    #pragma unroll 5
    for (int s = 0; s < NS; ++s) {
        // flat int4 index f = s*256 + tid ; r = f>>4 = s*16 + hi
        int r  = s * 16 + hi;
        int wl = r / CV2;                    // compile-time -> magic mul
        int d  = r - wl * CV2;
        int dy = d / CV;
        int dx = d - dy * CV;
        const float* p = sb + dy * PITCH + dx + wl;
        int4 v;
        v.x = (int)p[0];
        v.y = (int)p[1];
        v.z = (int)p[2];
        v.w = (int)p[3];
        *reinterpret_cast<int4*>(ob + (size_t)(s * 256 + tid) * 4) = v;
    }
}

// Generic fallback (runtime cv or W not a multiple of 80): direct gather.
__global__ __launch_bounds__(256) void esw_kernel_gen(
    const float* __restrict__ x, int* __restrict__ out,
    int H, int W, int base, int cv)
{
    const int cv2 = cv * cv;
    const int NW = W * cv2 * 16;
    int idx = blockIdx.x * 256 + threadIdx.x;
    if (idx >= NW) return;
    const int b = blockIdx.z;
    const int h = blockIdx.y;

    int t  = idx & 15;
    int r  = idx >> 4;
    int d  = r % cv2;
    int w  = r / cv2;
    int dy = d / cv;
    int dx = d - dy * cv;
    int ky  = t >> 1;
    int kx0 = (t & 1) << 2;

    int yy  = h + base + dy + ky;
    int xx0 = w + base + dx + kx0;

    const float* __restrict__ xrow = x + ((size_t)b * H + yy) * (size_t)W;
    const bool rowok = ((unsigned)yy < (unsigned)H);

    int4 v;
    int xx;
    xx = xx0 + 0; v.x = (rowok && (unsigned)xx < (unsigned)W) ? (int)xrow[xx] : 0;
    xx = xx0 + 1; v.y = (rowok && (unsigned)xx < (unsigned)W) ? (int)xrow[xx] : 0;
    xx = xx0 + 2; v.z = (rowok && (unsigned)xx < (unsigned)W) ? (int)xrow[xx] : 0;
    xx = xx0 + 3; v.w = (rowok && (unsigned)xx < (unsigned)W) ? (int)xrow[xx] : 0;

    size_t o = (((size_t)b * H + h) * (size_t)NW + idx) * 4;
    *reinterpret_cast<int4*>(out + o) = v;
}

extern "C" void kernel_launch(void* const* d_in, const int* in_sizes, int n_in,
                              void* d_out, int out_size, void* d_ws, size_t ws_size,
                              hipStream_t stream)
{
    const float* x = (const float*)d_in[0];
    int* out = (int*)d_out;

    const int H = 192, W = 320;
    int B = in_sizes[0] / (H * W);
    if (B < 1) B = 1;

    // Derive cv from out_size = B*H*W*cv^2*64
    long cv2l = (long)out_size / ((long)in_sizes[0] * (TSZ * TSZ));
    int cv = 1;
    while ((long)(cv + 2) * (cv + 2) <= cv2l) cv += 2;
    int sr = (cv - 1) / 2;
    int base = -(sr + TSZ / 2);

    dim3 block(256);

    if ((W % 80) == 0 && (cv == 1 || cv == 3 || cv == 5 || cv == 7)) {
        dim3 grid(W / 80, H, B);
        switch (cv) {
            case 1: esw_v3<1><<<grid, block, 0, stream>>>(x, out, H, W, base); break;
            case 3: esw_v3<3><<<grid, block, 0, stream>>>(x, out, H, W, base); break;
            case 5: esw_v3<5><<<grid, block, 0, stream>>>(x, out, H, W, base); break;
            case 7: esw_v3<7><<<grid, block, 0, stream>>>(x, out, H, W, base); break;
        }
    } else {
        const int NW = W * cv * cv * 16;
        dim3 g2((NW + 255) / 256, H, B);
        esw_kernel_gen<<<g2, block, 0, stream>>>(x, out, H, W, base, cv);
    }
}